// Round 8
// baseline (510.114 us; speedup 1.0000x reference)
//
#include <hip/hip_runtime.h>
#include <cstddef>

#define IN_F 256
#define OUT_F 128
#define SCAN_CHUNK 1024
#define RANGES 8
#define NXCD 8
#define ACHUNK 2048
#define PB_CHUNKS 256
// legacy ranged-scatter fallback params
#define SCHUNKS 512

// ---------------- GEMM: support = X @ W  (fp32, vector FMA) ----------------
// BM=128, BN=128, BK=32. 256 threads; each thread 8x8 outputs.
// 64 FMA per 4 ds_read_b128; 33KB LDS -> ~4 blocks/CU; ~780 blocks total.
__global__ __launch_bounds__(256) void gemm_kernel(const float* __restrict__ X,
                                                   const float* __restrict__ W,
                                                   float* __restrict__ S,
                                                   int nrows) {
    __shared__ float Xs[32][132];   // [k][row], +4 pad; 528B row stride (16B-aligned)
    __shared__ float Ws[32][128];   // [k][col]
    const int t = threadIdx.x;
    const int bm = blockIdx.x * 128;
    const int tr = (t >> 4) * 8;    // 16 thread-rows x 8
    const int tc = (t & 15) * 8;    // 16 thread-cols x 8
    float acc[8][8] = {};

    for (int kt = 0; kt < IN_F; kt += 32) {
        // stage X transposed: 128 rows x 8 float4 = 1024 float4; 4 per thread
#pragma unroll
        for (int l = 0; l < 4; ++l) {
            const int idx = t + l * 256;
            const int r = idx >> 3;
            const int k4 = idx & 7;
            int rr = bm + r; if (rr >= nrows) rr = nrows - 1;
            const float4 v = *reinterpret_cast<const float4*>(
                &X[(size_t)rr * IN_F + kt + k4 * 4]);
            Xs[k4 * 4 + 0][r] = v.x;
            Xs[k4 * 4 + 1][r] = v.y;
            Xs[k4 * 4 + 2][r] = v.z;
            Xs[k4 * 4 + 3][r] = v.w;
        }
        // stage W: 32k x 128c = 1024 float4; 4 per thread
#pragma unroll
        for (int l = 0; l < 4; ++l) {
            const int q = t + l * 256;
            const int k = q >> 5;
            const int c = (q & 31) * 4;
            *reinterpret_cast<float4*>(&Ws[k][c]) =
                *reinterpret_cast<const float4*>(&W[(size_t)(kt + k) * OUT_F + c]);
        }
        __syncthreads();
#pragma unroll 2
        for (int kk = 0; kk < 32; ++kk) {
            const float4 xa = *reinterpret_cast<const float4*>(&Xs[kk][tr]);
            const float4 xb = *reinterpret_cast<const float4*>(&Xs[kk][tr + 4]);
            const float4 wa = *reinterpret_cast<const float4*>(&Ws[kk][tc]);
            const float4 wb = *reinterpret_cast<const float4*>(&Ws[kk][tc + 4]);
            const float xr8[8] = {xa.x, xa.y, xa.z, xa.w, xb.x, xb.y, xb.z, xb.w};
            const float wc8[8] = {wa.x, wa.y, wa.z, wa.w, wb.x, wb.y, wb.z, wb.w};
#pragma unroll
            for (int j = 0; j < 8; ++j) {
#pragma unroll
                for (int i = 0; i < 8; ++i) acc[j][i] += xr8[j] * wc8[i];
            }
        }
        __syncthreads();
    }
#pragma unroll
    for (int j = 0; j < 8; ++j) {
        const int row = bm + tr + j;
        if (row < nrows) {
            *reinterpret_cast<float4*>(&S[(size_t)row * OUT_F + tc]) =
                make_float4(acc[j][0], acc[j][1], acc[j][2], acc[j][3]);
            *reinterpret_cast<float4*>(&S[(size_t)row * OUT_F + tc + 4]) =
                make_float4(acc[j][4], acc[j][5], acc[j][6], acc[j][7]);
        }
    }
}

// ---------------- Pass A: bucket edges by dst-range + fused node histogram ----------------
// Each block stages ACHUNK edges in LDS (read once), counts per range, reserves
// contiguous bucket segments (one global atomic per range per block), emits trips.
// Block-contiguous ~3KB/bucket segments -> full-line writebacks.
__global__ __launch_bounds__(256) void bucket_kernel(const int* __restrict__ src,
                                                     const int* __restrict__ dst,
                                                     const float* __restrict__ w,
                                                     int* __restrict__ counts,
                                                     int* __restrict__ btails,
                                                     int2* __restrict__ bsrcw,
                                                     int* __restrict__ bdst,
                                                     int E, int npr, int bcap) {
    __shared__ int sdst[ACHUNK];
    __shared__ int ssrc[ACHUNK];
    __shared__ float swt[ACHUNK];
    __shared__ int bcnt[RANGES], bbase[RANGES], bcur[RANGES];
    const int t = threadIdx.x;
    const int start = blockIdx.x * ACHUNK;
    const int cnt = min(ACHUNK, E - start);
    if (t < RANGES) { bcnt[t] = 0; bcur[t] = 0; }
    for (int j = t; j < cnt; j += 256) {
        sdst[j] = dst[start + j];
        ssrc[j] = src[start + j];
        swt[j] = w[start + j];
    }
    __syncthreads();
    for (int j = t; j < cnt; j += 256) {
        const int d = sdst[j];
        atomicAdd(&bcnt[(unsigned)d / (unsigned)npr], 1);
        atomicAdd(&counts[d], 1);   // fused histogram for CSR offsets
    }
    __syncthreads();
    if (t < RANGES) bbase[t] = atomicAdd(&btails[t], bcnt[t]);
    __syncthreads();
    for (int j = t; j < cnt; j += 256) {
        const int d = sdst[j];
        const int r = (unsigned)d / (unsigned)npr;
        const int loc = atomicAdd(&bcur[r], 1);
        const size_t pos = (size_t)r * bcap + bbase[r] + loc;
        bsrcw[pos] = make_int2(ssrc[j], __float_as_int(swt[j]));
        bdst[pos] = d;
    }
}

// ---------------- Pass B: place bucket items at CSR positions (XCD-affine) ----------------
// blockIdx = chunk*8 + r -> bucket r on XCD r: r's 1.6MB pairs window + 50KB
// cursor slice stay in one L2; lines fill before writeback.
__global__ __launch_bounds__(256) void place_kernel(const int2* __restrict__ bsrcw,
                                                    const int* __restrict__ bdst,
                                                    const int* __restrict__ btails,
                                                    int* __restrict__ cursor,
                                                    int2* __restrict__ pairs,
                                                    int bcap) {
    const int r = blockIdx.x & (RANGES - 1);
    const int chunk = blockIdx.x >> 3;
    const int sz = btails[r];
    const int per = (sz + PB_CHUNKS - 1) / PB_CHUNKS;
    const int s = chunk * per;
    const int e = min(sz, s + per);
    const size_t base = (size_t)r * bcap;
    for (int i = s + threadIdx.x; i < e; i += 256) {
        const int2 sw = bsrcw[base + i];
        const int d = bdst[base + i];
        const int pos = atomicAdd(&cursor[d], 1);
        pairs[pos] = sw;
    }
}

// ---------------- CSR scans ----------------
__global__ __launch_bounds__(256) void scan1_kernel(const int* __restrict__ counts,
                                                    int* __restrict__ off,
                                                    int* __restrict__ bsums, int n) {
    __shared__ int sd[256];
    const int t = threadIdx.x;
    const int base = blockIdx.x * SCAN_CHUNK + t * 4;
    int c[4]; int s = 0;
#pragma unroll
    for (int j = 0; j < 4; ++j) {
        c[j] = (base + j < n) ? counts[base + j] : 0;
        s += c[j];
    }
    sd[t] = s;
    __syncthreads();
    for (int d = 1; d < 256; d <<= 1) {
        int v = (t >= d) ? sd[t - d] : 0;
        __syncthreads();
        sd[t] += v;
        __syncthreads();
    }
    int run = sd[t] - s;
#pragma unroll
    for (int j = 0; j < 4; ++j) {
        if (base + j < n) off[base + j] = run;
        run += c[j];
    }
    if (t == 255) bsums[blockIdx.x] = sd[255];
}

__global__ __launch_bounds__(256) void scan2_kernel(int* __restrict__ bsums, int nb) {
    __shared__ int sd[256];
    const int t = threadIdx.x;
    const int v = (t < nb) ? bsums[t] : 0;
    sd[t] = v;
    __syncthreads();
    for (int d = 1; d < 256; d <<= 1) {
        int u = (t >= d) ? sd[t - d] : 0;
        __syncthreads();
        sd[t] += u;
        __syncthreads();
    }
    if (t < nb) bsums[t] = sd[t] - v;
}

__global__ __launch_bounds__(256) void scan3_kernel(int* __restrict__ off,
                                                    int* __restrict__ cursor,
                                                    const int* __restrict__ bsums,
                                                    int n, int total) {
    const int t = threadIdx.x;
    const int base = blockIdx.x * SCAN_CHUNK + t * 4;
    const int add = bsums[blockIdx.x];
#pragma unroll
    for (int j = 0; j < 4; ++j) {
        const int idx = base + j;
        if (idx < n) {
            const int v = off[idx] + add;
            off[idx] = v;
            cursor[idx] = v;
        }
    }
    if (blockIdx.x == 0 && t == 0) off[n] = total;
}

// ---------------- Legacy ranged scatter (fallback if buckets don't fit ws) ----------------
__global__ __launch_bounds__(256) void scatter_kernel(const int* __restrict__ src,
                                                      const int* __restrict__ dst,
                                                      const float* __restrict__ w,
                                                      int* __restrict__ cursor,
                                                      int2* __restrict__ pairs,
                                                      int E, int nodes_per_range) {
    const int range = blockIdx.x % NXCD;
    const int chunk = blockIdx.x / NXCD;
    const int r_lo = range * nodes_per_range;
    const int r_hi = r_lo + nodes_per_range;
    const int per_chunk = (E + SCHUNKS - 1) / SCHUNKS;
    const int start = chunk * per_chunk;
    const int end = min(E, start + per_chunk);
    for (int i = start + threadIdx.x; i < end; i += 256) {
        const int d = dst[i];
        if (d >= r_lo && d < r_hi) {
            const int pos = atomicAdd(&cursor[d], 1);
            int2 p;
            p.x = src[i];
            p.y = __float_as_int(w[i]);
            pairs[pos] = p;
        }
    }
}

__global__ void hist_kernel(const int* __restrict__ dst, int* __restrict__ counts, int E) {
    int i = blockIdx.x * blockDim.x + threadIdx.x;
    const int stride = gridDim.x * blockDim.x;
    for (; i < E; i += stride) atomicAdd(&counts[dst[i]], 1);
}

// ---------------- Gather (unchanged control): out[n] = sum w_e*S[src_e] + B ----------------
__global__ __launch_bounds__(256) void gather_kernel(const float* __restrict__ S,
                                                     const int* __restrict__ off,
                                                     const int2* __restrict__ pairs,
                                                     const float* __restrict__ B,
                                                     float* __restrict__ out, int n) {
    const int node = blockIdx.x * 4 + (threadIdx.x >> 6);
    const int lane = threadIdx.x & 63;
    if (node >= n) return;
    const int s = off[node];
    const int e = off[node + 1];
    const size_t fo = (size_t)lane * 2;
    float a0x = 0.f, a0y = 0.f, a1x = 0.f, a1y = 0.f;
    float a2x = 0.f, a2y = 0.f, a3x = 0.f, a3y = 0.f;
    int i = s;
    for (; i + 8 <= e; i += 8) {
        const int2 p0 = pairs[i];
        const int2 p1 = pairs[i + 1];
        const int2 p2 = pairs[i + 2];
        const int2 p3 = pairs[i + 3];
        const int2 p4 = pairs[i + 4];
        const int2 p5 = pairs[i + 5];
        const int2 p6 = pairs[i + 6];
        const int2 p7 = pairs[i + 7];
        const float2 v0 = *reinterpret_cast<const float2*>(&S[(size_t)p0.x * OUT_F + fo]);
        const float2 v1 = *reinterpret_cast<const float2*>(&S[(size_t)p1.x * OUT_F + fo]);
        const float2 v2 = *reinterpret_cast<const float2*>(&S[(size_t)p2.x * OUT_F + fo]);
        const float2 v3 = *reinterpret_cast<const float2*>(&S[(size_t)p3.x * OUT_F + fo]);
        const float2 v4 = *reinterpret_cast<const float2*>(&S[(size_t)p4.x * OUT_F + fo]);
        const float2 v5 = *reinterpret_cast<const float2*>(&S[(size_t)p5.x * OUT_F + fo]);
        const float2 v6 = *reinterpret_cast<const float2*>(&S[(size_t)p6.x * OUT_F + fo]);
        const float2 v7 = *reinterpret_cast<const float2*>(&S[(size_t)p7.x * OUT_F + fo]);
        a0x += __int_as_float(p0.y) * v0.x; a0y += __int_as_float(p0.y) * v0.y;
        a1x += __int_as_float(p1.y) * v1.x; a1y += __int_as_float(p1.y) * v1.y;
        a2x += __int_as_float(p2.y) * v2.x; a2y += __int_as_float(p2.y) * v2.y;
        a3x += __int_as_float(p3.y) * v3.x; a3y += __int_as_float(p3.y) * v3.y;
        a0x += __int_as_float(p4.y) * v4.x; a0y += __int_as_float(p4.y) * v4.y;
        a1x += __int_as_float(p5.y) * v5.x; a1y += __int_as_float(p5.y) * v5.y;
        a2x += __int_as_float(p6.y) * v6.x; a2y += __int_as_float(p6.y) * v6.y;
        a3x += __int_as_float(p7.y) * v7.x; a3y += __int_as_float(p7.y) * v7.y;
    }
    if (i + 4 <= e) {
        const int2 p0 = pairs[i];
        const int2 p1 = pairs[i + 1];
        const int2 p2 = pairs[i + 2];
        const int2 p3 = pairs[i + 3];
        const float2 v0 = *reinterpret_cast<const float2*>(&S[(size_t)p0.x * OUT_F + fo]);
        const float2 v1 = *reinterpret_cast<const float2*>(&S[(size_t)p1.x * OUT_F + fo]);
        const float2 v2 = *reinterpret_cast<const float2*>(&S[(size_t)p2.x * OUT_F + fo]);
        const float2 v3 = *reinterpret_cast<const float2*>(&S[(size_t)p3.x * OUT_F + fo]);
        a0x += __int_as_float(p0.y) * v0.x; a0y += __int_as_float(p0.y) * v0.y;
        a1x += __int_as_float(p1.y) * v1.x; a1y += __int_as_float(p1.y) * v1.y;
        a2x += __int_as_float(p2.y) * v2.x; a2y += __int_as_float(p2.y) * v2.y;
        a3x += __int_as_float(p3.y) * v3.x; a3y += __int_as_float(p3.y) * v3.y;
        i += 4;
    }
    for (; i < e; ++i) {
        const int2 p = pairs[i];
        const float2 v = *reinterpret_cast<const float2*>(&S[(size_t)p.x * OUT_F + fo]);
        const float wv = __int_as_float(p.y);
        a0x += wv * v.x; a0y += wv * v.y;
    }
    const float2 b2 = *reinterpret_cast<const float2*>(&B[fo]);
    float2 o;
    o.x = (a0x + a1x) + (a2x + a3x) + b2.x;
    o.y = (a0y + a1y) + (a2y + a3y) + b2.y;
    *reinterpret_cast<float2*>(&out[(size_t)node * OUT_F + fo]) = o;
}

// ---------------- Last-resort fallback: direct f32 atomics ----------------
__global__ void init_out_kernel(float* __restrict__ out, const float* __restrict__ B, size_t n) {
    size_t i = (size_t)blockIdx.x * blockDim.x + threadIdx.x;
    const size_t stride = (size_t)gridDim.x * blockDim.x;
    for (; i < n; i += stride) out[i] = B[i & (OUT_F - 1)];
}

__global__ void atomic_scatter_kernel(const float* __restrict__ S, const int* __restrict__ src,
                                      const int* __restrict__ dst, const float* __restrict__ w,
                                      float* __restrict__ out, int E) {
    size_t i = (size_t)blockIdx.x * blockDim.x + threadIdx.x;
    const size_t stride = (size_t)gridDim.x * blockDim.x;
    const size_t total = (size_t)E * OUT_F;
    for (; i < total; i += stride) {
        const int e = (int)(i >> 7);
        const int f = (int)(i & 127);
        atomicAdd(&out[(size_t)dst[e] * OUT_F + f], w[e] * S[(size_t)src[e] * OUT_F + f]);
    }
}

extern "C" void kernel_launch(void* const* d_in, const int* in_sizes, int n_in,
                              void* d_out, int out_size, void* d_ws, size_t ws_size,
                              hipStream_t stream) {
    const float* X    = (const float*)d_in[0];
    const float* W    = (const float*)d_in[1];
    const float* B    = (const float*)d_in[2];
    const int*   esrc = (const int*)d_in[3];
    const int*   edst = (const int*)d_in[4];
    const float* ew   = (const float*)d_in[5];
    float* out = (float*)d_out;

    const int N = in_sizes[0] / IN_F;
    const int E = in_sizes[3];

    char* ws = (char*)d_ws;
    size_t cur = 0;
    auto carve = [&](size_t bytes) -> void* {
        void* p = ws + cur;
        cur = (cur + bytes + 255) & ~(size_t)255;
        return p;
    };
    float* support = (float*)carve((size_t)N * OUT_F * sizeof(float));
    int*   counts  = (int*)carve((size_t)N * sizeof(int));
    int*   offs    = (int*)carve((size_t)(N + 1) * sizeof(int));
    int*   cursor  = (int*)carve((size_t)N * sizeof(int));
    int*   bsums   = (int*)carve(1024 * sizeof(int));
    int*   btails  = (int*)carve(RANGES * sizeof(int));
    int2*  pairs   = (int2*)carve((size_t)E * sizeof(int2));
    const size_t base_need = cur;
    const int bcap = E / RANGES + 16384;   // ~40 sigma margin for uniform dst
    int2*  bsrcw   = (int2*)carve((size_t)RANGES * bcap * sizeof(int2));
    int*   bdst    = (int*)carve((size_t)RANGES * bcap * sizeof(int));
    const bool bucket_ok = (cur <= ws_size);
    const bool csr_ok = (base_need <= ws_size);

    const int gemm_grid = (N + 127) / 128;
    gemm_kernel<<<gemm_grid, 256, 0, stream>>>(X, W, support, N);

    if (bucket_ok) {
        hipMemsetAsync(counts, 0, (size_t)N * sizeof(int), stream);
        hipMemsetAsync(btails, 0, RANGES * sizeof(int), stream);
        const int npr = (N + RANGES - 1) / RANGES;
        const int na = (E + ACHUNK - 1) / ACHUNK;
        bucket_kernel<<<na, 256, 0, stream>>>(esrc, edst, ew, counts, btails,
                                              bsrcw, bdst, E, npr, bcap);
        const int nb = (N + SCAN_CHUNK - 1) / SCAN_CHUNK;
        scan1_kernel<<<nb, 256, 0, stream>>>(counts, offs, bsums, N);
        scan2_kernel<<<1, 256, 0, stream>>>(bsums, nb);
        scan3_kernel<<<nb, 256, 0, stream>>>(offs, cursor, bsums, N, E);
        place_kernel<<<RANGES * PB_CHUNKS, 256, 0, stream>>>(bsrcw, bdst, btails,
                                                             cursor, pairs, bcap);
        gather_kernel<<<(N + 3) / 4, 256, 0, stream>>>(support, offs, pairs, B, out, N);
    } else if (csr_ok) {
        hipMemsetAsync(counts, 0, (size_t)N * sizeof(int), stream);
        hist_kernel<<<2048, 256, 0, stream>>>(edst, counts, E);
        const int nb = (N + SCAN_CHUNK - 1) / SCAN_CHUNK;
        scan1_kernel<<<nb, 256, 0, stream>>>(counts, offs, bsums, N);
        scan2_kernel<<<1, 256, 0, stream>>>(bsums, nb);
        scan3_kernel<<<nb, 256, 0, stream>>>(offs, cursor, bsums, N, E);
        const int npr = (N + RANGES - 1) / RANGES;
        scatter_kernel<<<SCHUNKS * NXCD, 256, 0, stream>>>(esrc, edst, ew, cursor, pairs, E, npr);
        gather_kernel<<<(N + 3) / 4, 256, 0, stream>>>(support, offs, pairs, B, out, N);
    } else {
        init_out_kernel<<<2048, 256, 0, stream>>>(out, B, (size_t)N * OUT_F);
        atomic_scatter_kernel<<<4096, 256, 0, stream>>>(support, esrc, edst, ew, out, E);
    }
}